// Round 1
// 108.008 us; speedup vs baseline: 1.0327x; 1.0327x over previous
//
#include <hip/hip_runtime.h>
#include <hip/hip_bf16.h>
#include <stdint.h>

// TargetTokenEncoder: histogram-stats -> MLP(14->256 GELU ->256) fused.
// R6: max-occupancy small blocks. 32 rows / 256 threads / ~17KB LDS ->
// 8 blocks/CU = 32 waves/CU. Hist split 8 lanes/row over all waves; h is
// repacked in-register (shfl_xor 32) into GEMM2 B-frag layout and staged in
// LDS fragment-major (conflict-free b128 write/read). Phase 3: 16 short
// steps, acc[2] (32 regs) -> fits (256,8) without spill.
// R7: coalesced epilogue. Old epilogue scattered 64x16B per store instr
// (each lane owns one row m=l31 -> 64 distinct 128B lines/instr, 2048
// 16B write transactions per block). Now acc is staged through the dead
// hb buffer (reused as float stage[16][260], pad-stride 260 so both LDS
// sides run at the 16B/lane throughput floor) in two 16-row passes, and
// out is written as 64-lane x float4 contiguous 1KB segments (256
// line-coalesced transactions per block, 8x fewer).

#define SSUP 128
#define DD   256

typedef __attribute__((ext_vector_type(8)))  short bf16x8;   // 8 bf16 = 4 VGPRs
typedef __attribute__((ext_vector_type(16))) float f32x16;   // C/D for 32x32 MFMA

__device__ __forceinline__ unsigned f2bf_u(float f) {
    union { float f; unsigned u; } v; v.f = f;
    return (v.u + 0x7FFFu + ((v.u >> 16) & 1u)) >> 16;   // RNE, no NaNs here
}
__device__ __forceinline__ unsigned pk2(float a, float b) {
    return f2bf_u(a) | (f2bf_u(b) << 16);
}
// Fast packed bf16 pair (v_cvt_pk_bf16_f32 on gfx950), RNE.
__device__ __forceinline__ unsigned pk2f(float a, float b) {
    union { __hip_bfloat162 h; unsigned u; } cv;
    cv.h = __float22bfloat162_rn(make_float2(a, b));
    return cv.u;
}

// tanh-form GELU: gelu(x) = x / (1 + exp(x*(A + B x^2))).
// |dev from exact erf-GELU| < 0.003 << tolerance. Saturates correctly.
__device__ __forceinline__ float gelu_f(float x) {
    float t = x * x;
    float u = __builtin_fmaf(t, -0.0713548162726f, -1.5957691216057f);
    float e = __expf(x * u);
    return x * __builtin_amdgcn_rcpf(1.0f + e);
}

// Fragment-major weights (A-operand: i = n = 32nt + (l&31), k = (l>>5)*8+j):
//   w2f[((s*8 + nt)*64 + l)*8 + j] = bf16(w2[(s*16 + (l>>5)*8 + j)*256 + n])
//   w1f[(nt*64 + l)*8 + j]         = bf16(w1[((l>>5)*8+j)*256 + n]), pad k>=14
__global__ void prep_kernel(const float* __restrict__ w1,
                            const float* __restrict__ w2,
                            unsigned short* __restrict__ w1f,
                            unsigned short* __restrict__ w2f) {
    int tid = blockIdx.x * 256 + threadIdx.x;
    if (tid < 8192) {                       // w2f: one thread per (s,nt,lane)
        int l  = tid & 63;
        int nt = (tid >> 6) & 7;
        int s  = tid >> 9;
        int n  = nt * 32 + (l & 31);
        int k0 = s * 16 + (l >> 5) * 8;
        unsigned pk[4];
        #pragma unroll
        for (int h = 0; h < 4; ++h)
            pk[h] = pk2(w2[(size_t)(k0 + 2*h) * DD + n],
                        w2[(size_t)(k0 + 2*h + 1) * DD + n]);
        *(uint4*)&w2f[(size_t)tid * 8] = make_uint4(pk[0], pk[1], pk[2], pk[3]);
    } else if (tid < 8704) {                // w1f
        int idx = tid - 8192;
        int l   = idx & 63;
        int nt  = idx >> 6;
        int n   = nt * 32 + (l & 31);
        int kk0 = (l >> 5) * 8;
        unsigned pk[4];
        #pragma unroll
        for (int h = 0; h < 4; ++h) {
            int ka = kk0 + 2*h, kb = kk0 + 2*h + 1;
            float fa = (ka < 14) ? w1[(size_t)ka * DD + n] : 0.0f;
            float fb = (kb < 14) ? w1[(size_t)kb * DD + n] : 0.0f;
            pk[h] = pk2(fa, fb);
        }
        *(uint4*)&w1f[(size_t)idx * 8] = make_uint4(pk[0], pk[1], pk[2], pk[3]);
    }
}

__global__ __launch_bounds__(256, 8)
void encoder_kernel(const int* __restrict__ y,
                    const float* __restrict__ b1,
                    const float* __restrict__ b2,
                    const unsigned short* __restrict__ w1f,
                    const unsigned short* __restrict__ w2f,
                    float* __restrict__ out) {
    // stats_lds[row*2+half]: 4 packed u32 = 8 bf16 of the stats vector half.
    __shared__ __align__(16) unsigned stats_lds[64][4];            // 1 KB
    // stage overlays hb: phase 2/3 use it as GEMM2 B-frag store
    // (hb[((s*2+lh)*32+m)*8 ..+7], 16 KB); the epilogue reuses it as
    // float stage[16][260] (16.25 KB, stride-260 pad).
    __shared__ __align__(16) float stage[16 * 260];                // 16.25 KB
    unsigned short* hb = (unsigned short*)stage;

    const int tid  = threadIdx.x;
    const int lane = tid & 63;
    const int wid  = tid >> 6;   // 0..3 = N-quarter owner
    const int l31  = lane & 31;
    const int lh   = lane >> 5;
    const int rbase = blockIdx.x * 32;

    // ---------------- Phase 1: histogram, 8 lanes/row over all waves --------
    const int hrow = wid * 8 + (lane >> 3);   // 0..31
    const int sub  = lane & 7;
    const int4* yp = (const int4*)(y + (size_t)(rbase + hrow) * SSUP);
    unsigned long long pk = 0ull;             // 10 counters, 6-bit packed
    #pragma unroll
    for (int i = 0; i < 4; ++i) {
        int4 v = yp[i * 8 + sub];             // 8-lane group: 128B contiguous
        pk += 1ull << (6 * v.x);
        pk += 1ull << (6 * v.y);
        pk += 1ull << (6 * v.z);
        pk += 1ull << (6 * v.w);
    }
    pk += __shfl_xor((long long)pk, 1);       // per-class <=32, still fits 6b
    float p[10]; float ent = 0.f, pmax = 0.f, nnz = 0.f;
    #pragma unroll
    for (int c = 0; c < 10; ++c) {
        int cc = (int)((pk >> (6 * c)) & 63ull);
        cc += __shfl_xor(cc, 2);
        cc += __shfl_xor(cc, 4);              // full row total (<=128) in 32b
        float pc = (float)cc * 0.0078125f;    // total is always 128
        p[c] = pc;
        nnz += (cc > 0) ? 1.0f : 0.0f;
        ent -= pc * __logf(pc + 1e-6f);
        pmax = fmaxf(pmax, pc);
    }
    if (sub < 2) {
        uint4 st;
        if (sub == 0) st = make_uint4(pk2f(p[0], p[1]), pk2f(p[2], p[3]),
                                      pk2f(p[4], p[5]), pk2f(p[6], p[7]));
        else          st = make_uint4(pk2f(p[8], p[9]), pk2f(nnz, ent),
                                      pk2f(128.0f, pmax), 0u);
        *(uint4*)&stats_lds[hrow * 2 + sub][0] = st;
    }
    __syncthreads();

    // Stats B-frag: lane (m=l31, lh) takes half lh of row m's stats.
    union { unsigned u[4]; bf16x8 v; } sf;
    *(uint4*)sf.u = *(const uint4*)&stats_lds[l31 * 2 + lh][0];
    const bf16x8 sfrag = sf.v;

    // ---------------- Phase 2: GEMM1 + GELU -> B-frag-ready h in LDS --------
    // D1[i=n][j=m] per tile nt (wave owns nt = 2wid, 2wid+1). Repack lane's
    // 16 outputs into GEMM2 B-frag chunks via shfl_xor(32), write b128.
    #pragma unroll
    for (int t = 0; t < 2; ++t) {
        const int nt = wid * 2 + t;
        union { unsigned u[4]; bf16x8 v; } wf;
        *(uint4*)wf.u = *(const uint4*)&w1f[(size_t)(nt * 64 + lane) * 8];
        f32x16 c;
        #pragma unroll
        for (int g = 0; g < 4; ++g) {
            float4 bv = *(const float4*)&b1[nt * 32 + 8 * g + 4 * lh];
            c[4*g+0] = bv.x; c[4*g+1] = bv.y; c[4*g+2] = bv.z; c[4*g+3] = bv.w;
        }
        c = __builtin_amdgcn_mfma_f32_32x32x16_bf16(wf.v, sfrag, c, 0, 0, 0);
        unsigned own[8], rcv[8];
        #pragma unroll
        for (int g = 0; g < 4; ++g) {
            own[2*g+0] = pk2f(gelu_f(c[4*g+0]), gelu_f(c[4*g+1]));
            own[2*g+1] = pk2f(gelu_f(c[4*g+2]), gelu_f(c[4*g+3]));
        }
        #pragma unroll
        for (int j = 0; j < 8; ++j) rcv[j] = (unsigned)__shfl_xor((int)own[j], 32);
        #pragma unroll
        for (int tt = 0; tt < 2; ++tt) {
            const int s = 2 * nt + tt;
            uint4 fr;
            fr.x = lh ? rcv[4*tt+2] : own[4*tt+0];
            fr.y = lh ? rcv[4*tt+3] : own[4*tt+1];
            fr.z = lh ? own[4*tt+2] : rcv[4*tt+0];
            fr.w = lh ? own[4*tt+3] : rcv[4*tt+1];
            *(uint4*)&hb[(size_t)((s * 2 + lh) * 32 + l31) * 8] = fr;
        }
    }
    __syncthreads();

    // ---------------- Phase 3: GEMM2 ----------------
    f32x16 acc[2];
    #pragma unroll
    for (int u = 0; u < 2; ++u) {
        const int nt = wid * 2 + u;
        #pragma unroll
        for (int g = 0; g < 4; ++g) {
            float4 bv = *(const float4*)&b2[nt * 32 + 8 * g + 4 * lh];
            acc[u][4*g+0] = bv.x; acc[u][4*g+1] = bv.y;
            acc[u][4*g+2] = bv.z; acc[u][4*g+3] = bv.w;
        }
    }
    #pragma unroll
    for (int s = 0; s < 16; ++s) {
        union { unsigned u[4]; bf16x8 v; } hf;
        *(uint4*)hf.u = *(const uint4*)&hb[(size_t)((s * 2 + lh) * 32 + l31) * 8];
        #pragma unroll
        for (int u = 0; u < 2; ++u) {
            const int nt = wid * 2 + u;
            union { unsigned u[4]; bf16x8 v; } wf;
            *(uint4*)wf.u = *(const uint4*)&w2f[(size_t)((s * 8 + nt) * 64 + lane) * 8];
            acc[u] = __builtin_amdgcn_mfma_f32_32x32x16_bf16(wf.v, hf.v, acc[u], 0, 0, 0);
        }
    }

    // ---------------- Epilogue: LDS-restage -> coalesced stores -------------
    // Lane owns row m=l31, cols {nt*32+8g+4lh..+3}. Two passes of 16 rows
    // through stage[16][260] (stride 260: write banks (4r+8g+4lh)%32 -> 4
    // lanes per 4-bank group = 32-lane b128 floor; read = contiguous row,
    // 8 lanes per group = 64-lane b128 floor). Stores become 64-lane x
    // float4 contiguous (1KB/instr, line-coalesced).
    #pragma unroll
    for (int h = 0; h < 2; ++h) {
        __syncthreads();                      // hb / prev-pass reads done
        if ((l31 >> 4) == h) {
            const int r = l31 & 15;
            #pragma unroll
            for (int u = 0; u < 2; ++u) {
                const int nt = wid * 2 + u;
                #pragma unroll
                for (int g = 0; g < 4; ++g) {
                    float4 o;
                    o.x = acc[u][4*g+0]; o.y = acc[u][4*g+1];
                    o.z = acc[u][4*g+2]; o.w = acc[u][4*g+3];
                    *(float4*)&stage[r * 260 + nt * 32 + 8 * g + 4 * lh] = o;
                }
            }
        }
        __syncthreads();
        #pragma unroll
        for (int g2 = 0; g2 < 4; ++g2) {
            const int rl = wid * 4 + g2;      // 0..15
            float4 v = *(const float4*)&stage[rl * 260 + lane * 4];
            *(float4*)&out[(size_t)(rbase + h * 16 + rl) * DD + lane * 4] = v;
        }
    }
}

extern "C" void kernel_launch(void* const* d_in, const int* in_sizes, int n_in,
                              void* d_out, int out_size, void* d_ws, size_t ws_size,
                              hipStream_t stream) {
    const int*   y  = (const int*)d_in[0];
    const float* w1 = (const float*)d_in[1];
    const float* b1 = (const float*)d_in[2];
    const float* w2 = (const float*)d_in[3];
    const float* b2 = (const float*)d_in[4];
    float* out = (float*)d_out;

    unsigned short* w2f = (unsigned short*)d_ws;        // 65536 shorts (128 KB)
    unsigned short* w1f = w2f + 65536;                  // 4096 shorts (8 KB)

    prep_kernel<<<34, 256, 0, stream>>>(w1, w2, w1f, w2f);

    const int nrows = in_sizes[0] / SSUP;               // 65536
    encoder_kernel<<<nrows / 32, 256, 0, stream>>>(y, b1, b2, w1f, w2f, out);
}

// Round 4
// 107.696 us; speedup vs baseline: 1.0357x; 1.0029x over previous
//
#include <hip/hip_runtime.h>
#include <hip/hip_bf16.h>
#include <stdint.h>

// TargetTokenEncoder: histogram-stats -> MLP(14->256 GELU ->256) fused.
// R7: coalesced epilogue via LDS restage (out written as 64-lane float4
// contiguous segments).
// R8: 64 rows / block (256 threads, 4 waves). Each wave keeps its w2f
// A-fragments in registers and applies them to TWO row-group B-fragments
// (acc[2][2], 64 VGPRs) -> w2f L2/TCP traffic halves chip-wide (256->128MB),
// fragment-load instruction count per row halves, barriers amortize over 2x
// rows. 4 blocks/CU, __launch_bounds__(256,4).
// R8b FIX: epilogue stage stride was 132 (< row width 256) -> rows
// overlapped, wrong results. Now float stage[32*260] (33.3KB, covers the
// 32KB hb it overlays). Stride 260 == 4 mod 32: write side 8 lanes per
// 4-bank group (8-cycle b128 floor), read side contiguous rows (floor).
// R9: identical resubmit of R8b after infra-level container failure
// (source audited: no OOB, no divergent barriers, LDS 35.3KB*4 <= 160KB).

#define SSUP 128
#define DD   256

typedef __attribute__((ext_vector_type(8)))  short bf16x8;   // 8 bf16 = 4 VGPRs
typedef __attribute__((ext_vector_type(16))) float f32x16;   // C/D for 32x32 MFMA

__device__ __forceinline__ unsigned f2bf_u(float f) {
    union { float f; unsigned u; } v; v.f = f;
    return (v.u + 0x7FFFu + ((v.u >> 16) & 1u)) >> 16;   // RNE, no NaNs here
}
__device__ __forceinline__ unsigned pk2(float a, float b) {
    return f2bf_u(a) | (f2bf_u(b) << 16);
}
// Fast packed bf16 pair (v_cvt_pk_bf16_f32 on gfx950), RNE.
__device__ __forceinline__ unsigned pk2f(float a, float b) {
    union { __hip_bfloat162 h; unsigned u; } cv;
    cv.h = __float22bfloat162_rn(make_float2(a, b));
    return cv.u;
}

// tanh-form GELU: gelu(x) = x / (1 + exp(x*(A + B x^2))).
// |dev from exact erf-GELU| < 0.003 << tolerance. Saturates correctly.
__device__ __forceinline__ float gelu_f(float x) {
    float t = x * x;
    float u = __builtin_fmaf(t, -0.0713548162726f, -1.5957691216057f);
    float e = __expf(x * u);
    return x * __builtin_amdgcn_rcpf(1.0f + e);
}

// Fragment-major weights (A-operand: i = n = 32nt + (l&31), k = (l>>5)*8+j):
//   w2f[((s*8 + nt)*64 + l)*8 + j] = bf16(w2[(s*16 + (l>>5)*8 + j)*256 + n])
//   w1f[(nt*64 + l)*8 + j]         = bf16(w1[((l>>5)*8+j)*256 + n]), pad k>=14
__global__ void prep_kernel(const float* __restrict__ w1,
                            const float* __restrict__ w2,
                            unsigned short* __restrict__ w1f,
                            unsigned short* __restrict__ w2f) {
    int tid = blockIdx.x * 256 + threadIdx.x;
    if (tid < 8192) {                       // w2f: one thread per (s,nt,lane)
        int l  = tid & 63;
        int nt = (tid >> 6) & 7;
        int s  = tid >> 9;
        int n  = nt * 32 + (l & 31);
        int k0 = s * 16 + (l >> 5) * 8;
        unsigned pk[4];
        #pragma unroll
        for (int h = 0; h < 4; ++h)
            pk[h] = pk2(w2[(size_t)(k0 + 2*h) * DD + n],
                        w2[(size_t)(k0 + 2*h + 1) * DD + n]);
        *(uint4*)&w2f[(size_t)tid * 8] = make_uint4(pk[0], pk[1], pk[2], pk[3]);
    } else if (tid < 8704) {                // w1f
        int idx = tid - 8192;
        int l   = idx & 63;
        int nt  = idx >> 6;
        int n   = nt * 32 + (l & 31);
        int kk0 = (l >> 5) * 8;
        unsigned pk[4];
        #pragma unroll
        for (int h = 0; h < 4; ++h) {
            int ka = kk0 + 2*h, kb = kk0 + 2*h + 1;
            float fa = (ka < 14) ? w1[(size_t)ka * DD + n] : 0.0f;
            float fb = (kb < 14) ? w1[(size_t)kb * DD + n] : 0.0f;
            pk[h] = pk2(fa, fb);
        }
        *(uint4*)&w1f[(size_t)idx * 8] = make_uint4(pk[0], pk[1], pk[2], pk[3]);
    }
}

__global__ __launch_bounds__(256, 4)
void encoder_kernel(const int* __restrict__ y,
                    const float* __restrict__ b1,
                    const float* __restrict__ b2,
                    const unsigned short* __restrict__ w1f,
                    const unsigned short* __restrict__ w2f,
                    float* __restrict__ out) {
    // stats_lds[row*2+half]: 4 packed u32 = 8 bf16 of the stats vector half.
    __shared__ __align__(16) unsigned stats_lds[128][4];              // 2 KB
    // stage (33.3 KB) doubles as hb: phase 2/3 overlay
    // hb[rg][((s*2+lh)*32+m)*8 ..+7] (GEMM2 B-frags, 16 KB per row-group);
    // the epilogue uses it as float stage[32][260] (stride-260 pad).
    __shared__ __align__(16) float stage[32 * 260];                   // 33.3 KB
    unsigned short* hb0 = (unsigned short*)stage;                     // rg=0
    unsigned short* hb1 = hb0 + 16 * 2 * 32 * 8;                      // rg=1

    const int tid  = threadIdx.x;
    const int lane = tid & 63;
    const int wid  = tid >> 6;   // 0..3 = N-quarter owner
    const int l31  = lane & 31;
    const int lh   = lane >> 5;
    const int rbase = blockIdx.x * 64;

    // ---------------- Phase 1: histogram, 8 lanes/row, 2 rows/lane ---------
    const int sub = lane & 7;
    #pragma unroll
    for (int rr = 0; rr < 2; ++rr) {
        const int hrow = wid * 16 + rr * 8 + (lane >> 3);   // 0..63
        const int4* yp = (const int4*)(y + (size_t)(rbase + hrow) * SSUP);
        unsigned long long pk = 0ull;         // 10 counters, 6-bit packed
        #pragma unroll
        for (int i = 0; i < 4; ++i) {
            int4 v = yp[i * 8 + sub];         // 8-lane group: 128B contiguous
            pk += 1ull << (6 * v.x);
            pk += 1ull << (6 * v.y);
            pk += 1ull << (6 * v.z);
            pk += 1ull << (6 * v.w);
        }
        pk += __shfl_xor((long long)pk, 1);   // per-class <=32, still fits 6b
        float p[10]; float ent = 0.f, pmax = 0.f, nnz = 0.f;
        #pragma unroll
        for (int c = 0; c < 10; ++c) {
            int cc = (int)((pk >> (6 * c)) & 63ull);
            cc += __shfl_xor(cc, 2);
            cc += __shfl_xor(cc, 4);          // full row total (<=128) in 32b
            float pc = (float)cc * 0.0078125f;    // total is always 128
            p[c] = pc;
            nnz += (cc > 0) ? 1.0f : 0.0f;
            ent -= pc * __logf(pc + 1e-6f);
            pmax = fmaxf(pmax, pc);
        }
        if (sub < 2) {
            uint4 st;
            if (sub == 0) st = make_uint4(pk2f(p[0], p[1]), pk2f(p[2], p[3]),
                                          pk2f(p[4], p[5]), pk2f(p[6], p[7]));
            else          st = make_uint4(pk2f(p[8], p[9]), pk2f(nnz, ent),
                                          pk2f(128.0f, pmax), 0u);
            *(uint4*)&stats_lds[hrow * 2 + sub][0] = st;
        }
    }
    __syncthreads();

    // Stats B-frags: lane (m=l31, lh) takes half lh of row (rg*32+m)'s stats.
    bf16x8 sfrag[2];
    #pragma unroll
    for (int rg = 0; rg < 2; ++rg) {
        union { unsigned u[4]; bf16x8 v; } sf;
        *(uint4*)sf.u = *(const uint4*)&stats_lds[(rg * 32 + l31) * 2 + lh][0];
        sfrag[rg] = sf.v;
    }

    // ---------------- Phase 2: GEMM1 + GELU -> B-frag-ready h in LDS --------
    // D1[i=n][j=m] per tile nt (wave owns nt = 2wid, 2wid+1), per row-group.
    // Repack lane's 16 outputs into GEMM2 B-frag chunks via shfl_xor(32).
    #pragma unroll
    for (int t = 0; t < 2; ++t) {
        const int nt = wid * 2 + t;
        union { unsigned u[4]; bf16x8 v; } wf;
        *(uint4*)wf.u = *(const uint4*)&w1f[(size_t)(nt * 64 + lane) * 8];
        #pragma unroll
        for (int rg = 0; rg < 2; ++rg) {
            unsigned short* hb = rg ? hb1 : hb0;
            f32x16 c;
            #pragma unroll
            for (int g = 0; g < 4; ++g) {
                float4 bv = *(const float4*)&b1[nt * 32 + 8 * g + 4 * lh];
                c[4*g+0] = bv.x; c[4*g+1] = bv.y;
                c[4*g+2] = bv.z; c[4*g+3] = bv.w;
            }
            c = __builtin_amdgcn_mfma_f32_32x32x16_bf16(wf.v, sfrag[rg], c, 0, 0, 0);
            unsigned own[8], rcv[8];
            #pragma unroll
            for (int g = 0; g < 4; ++g) {
                own[2*g+0] = pk2f(gelu_f(c[4*g+0]), gelu_f(c[4*g+1]));
                own[2*g+1] = pk2f(gelu_f(c[4*g+2]), gelu_f(c[4*g+3]));
            }
            #pragma unroll
            for (int j = 0; j < 8; ++j) rcv[j] = (unsigned)__shfl_xor((int)own[j], 32);
            #pragma unroll
            for (int tt = 0; tt < 2; ++tt) {
                const int s = 2 * nt + tt;
                uint4 fr;
                fr.x = lh ? rcv[4*tt+2] : own[4*tt+0];
                fr.y = lh ? rcv[4*tt+3] : own[4*tt+1];
                fr.z = lh ? own[4*tt+2] : rcv[4*tt+0];
                fr.w = lh ? own[4*tt+3] : rcv[4*tt+1];
                *(uint4*)&hb[(size_t)((s * 2 + lh) * 32 + l31) * 8] = fr;
            }
        }
    }
    __syncthreads();

    // ---------------- Phase 3: GEMM2, shared w2f frags over 2 row-groups ---
    f32x16 acc[2][2];
    #pragma unroll
    for (int u = 0; u < 2; ++u) {
        const int nt = wid * 2 + u;
        #pragma unroll
        for (int g = 0; g < 4; ++g) {
            float4 bv = *(const float4*)&b2[nt * 32 + 8 * g + 4 * lh];
            #pragma unroll
            for (int rg = 0; rg < 2; ++rg) {
                acc[rg][u][4*g+0] = bv.x; acc[rg][u][4*g+1] = bv.y;
                acc[rg][u][4*g+2] = bv.z; acc[rg][u][4*g+3] = bv.w;
            }
        }
    }
    #pragma unroll
    for (int s = 0; s < 16; ++s) {
        union { unsigned u[4]; bf16x8 v; } hf[2], wf[2];
        *(uint4*)hf[0].u = *(const uint4*)&hb0[(size_t)((s * 2 + lh) * 32 + l31) * 8];
        *(uint4*)hf[1].u = *(const uint4*)&hb1[(size_t)((s * 2 + lh) * 32 + l31) * 8];
        #pragma unroll
        for (int u = 0; u < 2; ++u) {
            const int nt = wid * 2 + u;
            *(uint4*)wf[u].u = *(const uint4*)&w2f[(size_t)((s * 8 + nt) * 64 + lane) * 8];
        }
        #pragma unroll
        for (int rg = 0; rg < 2; ++rg)
            #pragma unroll
            for (int u = 0; u < 2; ++u)
                acc[rg][u] = __builtin_amdgcn_mfma_f32_32x32x16_bf16(
                    wf[u].v, hf[rg].v, acc[rg][u], 0, 0, 0);
    }

    // ---------------- Epilogue: LDS-restage -> coalesced stores -------------
    // Per row-group: all lanes write their acc tile into stage[32][260]
    // (stride 260 == 4 mod 32: write = 8 lanes per 4-bank group -> 8-cycle
    // b128 floor; read = contiguous 1KB rows, same floor), then store
    // 64-lane float4 contiguous segments (line-coalesced).
    #pragma unroll
    for (int rg = 0; rg < 2; ++rg) {
        __syncthreads();                      // hb / prev stage reads done
        #pragma unroll
        for (int u = 0; u < 2; ++u) {
            const int nt = wid * 2 + u;
            #pragma unroll
            for (int g = 0; g < 4; ++g) {
                float4 o;
                o.x = acc[rg][u][4*g+0]; o.y = acc[rg][u][4*g+1];
                o.z = acc[rg][u][4*g+2]; o.w = acc[rg][u][4*g+3];
                *(float4*)&stage[l31 * 260 + nt * 32 + 8 * g + 4 * lh] = o;
            }
        }
        __syncthreads();
        #pragma unroll
        for (int g2 = 0; g2 < 8; ++g2) {
            const int rl = wid * 8 + g2;      // 0..31
            float4 v = *(const float4*)&stage[rl * 260 + lane * 4];
            *(float4*)&out[(size_t)(rbase + rg * 32 + rl) * DD + lane * 4] = v;
        }
    }
}

extern "C" void kernel_launch(void* const* d_in, const int* in_sizes, int n_in,
                              void* d_out, int out_size, void* d_ws, size_t ws_size,
                              hipStream_t stream) {
    const int*   y  = (const int*)d_in[0];
    const float* w1 = (const float*)d_in[1];
    const float* b1 = (const float*)d_in[2];
    const float* w2 = (const float*)d_in[3];
    const float* b2 = (const float*)d_in[4];
    float* out = (float*)d_out;

    unsigned short* w2f = (unsigned short*)d_ws;        // 65536 shorts (128 KB)
    unsigned short* w1f = w2f + 65536;                  // 4096 shorts (8 KB)

    prep_kernel<<<34, 256, 0, stream>>>(w1, w2, w1f, w2f);

    const int nrows = in_sizes[0] / SSUP;               // 65536
    encoder_kernel<<<nrows / 64, 256, 0, stream>>>(y, b1, b2, w1f, w2f, out);
}